// Round 8
// baseline (299.851 us; speedup 1.0000x reference)
//
#include <hip/hip_runtime.h>
#include <hip/hip_bf16.h>

#define NNODES 50000
#define NEDGES 800000
#define F_IN 128
#define F_HID 256

using u16 = unsigned short;
using u32 = unsigned int;
using f32x4 = __attribute__((ext_vector_type(4))) float;
using s16x8 = __attribute__((ext_vector_type(8))) short;

constexpr int B2SHIFT = 9;                         // 512 nodes per coarse bucket
constexpr int NB2 = (NNODES + 511) >> 9;           // 98
constexpr int NBLK = 256;                          // scatter blocks
constexpr int EPB = NEDGES / NBLK;                 // 3125 edges per block (exact)

// ---------------- workspace layout (bytes) ----------------
constexpr size_t OFF_DINV   = 0;          // 200192
constexpr size_t OFF_ROWPTR = 200192;     // 200192
constexpr size_t OFF_CMAT   = 400384;     // 100352 (98*256*4)
constexpr size_t OFF_BTOT   = 500736;     // 1024
constexpr size_t OFF_BBASE  = 501760;     // 1024
constexpr size_t OFF_PAIRS  = 502784;     // 3200000 (800000 u32)
constexpr size_t OFF_PW     = 3702784;    // 3200000 (800000 u32 packed w|src)
constexpr size_t OFF_XB     = 6902784;    // 12800000 (50000x128 bf16)
constexpr size_t OFF_HB     = 19702784;   // 25600000 (50000x256 bf16)
constexpr size_t OFF_HB2    = 45302784;   // 25600000
constexpr size_t OFF_W1T    = 70902784;   // 65536
constexpr size_t OFF_W2T    = 70968320;   // 131072
constexpr size_t OFF_W3T    = 71099392;   // 131072
// total ~71.2 MB

static __device__ __forceinline__ float b2f(u16 u) {
    union { unsigned int i; float f; } v;
    v.i = ((unsigned int)u) << 16;
    return v.f;
}
static __device__ __forceinline__ u16 f2b(float f) {
    __hip_bfloat16 h = __float2bfloat16(f);  // round-to-nearest
    return __builtin_bit_cast(u16, h);
}

// per-block edge-dtype detect: true => int64 layout.
static __device__ __forceinline__ bool detect_wide(const void* raw) {
    __shared__ int bad;
    if (threadIdx.x == 0) bad = 0;
    __syncthreads();
    unsigned long long v = ((const unsigned long long*)raw)[threadIdx.x & 255];
    if (v >= (unsigned long long)NNODES) atomicAdd(&bad, 1);
    __syncthreads();
    return bad == 0;
}

// ---------------- A: hist (blocks 0..255) + all fp32->bf16 converts (blocks 256..7145) ----------------
__global__ __launch_bounds__(256) void hist_conv(const void* __restrict__ raw, int* __restrict__ cmat,
                                                 const float* __restrict__ x,
                                                 const float* __restrict__ W1, const float* __restrict__ W2,
                                                 const float* __restrict__ W3, u16* __restrict__ xb,
                                                 u16* __restrict__ W1t, u16* __restrict__ W2t,
                                                 u16* __restrict__ W3t) {
    int bid = blockIdx.x;
    int t = threadIdx.x;
    if (bid < NBLK) {
        const bool wide = detect_wide(raw);
        __shared__ int h[NB2];
        if (t < NB2) h[t] = 0;
        __syncthreads();
        const int base = bid * EPB;
        for (int i = t; i < EPB; i += 256) {
            int e = base + i;
            int d = wide ? (int)((const long long*)raw)[NEDGES + e] : ((const int*)raw)[NEDGES + e];
            atomicAdd(&h[d >> B2SHIFT], 1);
        }
        __syncthreads();
        if (t < NB2) cmat[t * NBLK + bid] = h[t];
    } else if (bid < NBLK + 6250) {
        int i = (bid - NBLK) * 256 + t;  // 1,600,000 float4 units exactly
        float4 v = ((const float4*)x)[i];
        ushort4 o;
        o.x = f2b(v.x); o.y = f2b(v.y); o.z = f2b(v.z); o.w = f2b(v.w);
        ((ushort4*)xb)[i] = o;
    } else {
        int idx = (bid - NBLK - 6250) * 256 + t;  // 163840 = 32768 + 65536 + 65536
        if (idx < 32768) {
            int k = idx >> 8, n = idx & 255;
            W1t[n * 128 + k] = f2b(W1[idx]);
        } else if (idx < 98304) {
            int j = idx - 32768;
            int k = j >> 8, n = j & 255;
            W2t[n * 256 + k] = f2b(W2[j]);
        } else {
            int j = idx - 98304;
            int k = j >> 8, n = j & 255;
            W3t[n * 256 + k] = f2b(W3[j]);
        }
    }
}

// B: per-bucket exclusive scan over the 256 block-counts (bucket-local); bucket total out
__global__ __launch_bounds__(256) void offset_kernel(int* __restrict__ cmat, int* __restrict__ btot) {
    __shared__ int s[256];
    int b = blockIdx.x, t = threadIdx.x;
    int v = cmat[b * NBLK + t];
    s[t] = v;
    __syncthreads();
    for (int o = 1; o < 256; o <<= 1) {
        int tmp = (t >= o) ? s[t - o] : 0;
        __syncthreads();
        s[t] += tmp;
        __syncthreads();
    }
    cmat[b * NBLK + t] = s[t] - v;  // exclusive, bucket-local
    if (t == 255) btot[b] = s[255];
}

// C: exclusive scan of 98 bucket totals -> bucket bases
__global__ void bscan_kernel(const int* __restrict__ btot, int* __restrict__ bbase) {
    __shared__ int s[128];
    int t = threadIdx.x;
    int v = (t < NB2) ? btot[t] : 0;
    s[t] = v;
    __syncthreads();
    for (int o = 1; o < 128; o <<= 1) {
        int tmp = (t >= o) ? s[t - o] : 0;
        __syncthreads();
        s[t] += tmp;
        __syncthreads();
    }
    if (t < NB2) bbase[t] = s[t] - v;
}

// D: scatter edges into exact bucket regions; cursors in LDS (block-private)
__global__ __launch_bounds__(256) void scatter_kernel(const void* __restrict__ raw,
                                                      const int* __restrict__ cmat,
                                                      const int* __restrict__ bbase,
                                                      u32* __restrict__ pairs) {
    const bool wide = detect_wide(raw);
    __shared__ int cur[NB2];
    int t = threadIdx.x;
    if (t < NB2) cur[t] = cmat[t * NBLK + blockIdx.x] + bbase[t];
    __syncthreads();
    const int base = blockIdx.x * EPB;
    for (int i = t; i < EPB; i += 256) {
        int e = base + i;
        int s, d;
        if (wide) {
            const long long* p = (const long long*)raw;
            s = (int)p[e];
            d = (int)p[NEDGES + e];
        } else {
            const int* p = (const int*)raw;
            s = p[e];
            d = p[NEDGES + e];
        }
        int pos = atomicAdd(&cur[d >> B2SHIFT], 1);
        pairs[pos] = ((u32)(d & 511) << 16) | (u32)s;  // src < 50000 < 2^16
    }
}

// E: per-bucket degree count (LDS) + 512-wide LDS scan -> row_ptr + dinv
__global__ __launch_bounds__(256) void phase2a(const u32* __restrict__ pairs,
                                               const int* __restrict__ bbase, const int* __restrict__ btot,
                                               int* __restrict__ row_ptr, float* __restrict__ dinv) {
    __shared__ int lcnt[512];
    __shared__ int ssc[512];
    int b = blockIdx.x, t = threadIdx.x;
    int n0 = b << B2SHIFT;
    lcnt[t] = 0; lcnt[t + 256] = 0;
    __syncthreads();
    int p0 = bbase[b], p1 = p0 + btot[b];
    for (int p = p0 + t; p < p1; p += 256)
        atomicAdd(&lcnt[pairs[p] >> 16], 1);
    __syncthreads();
    int c0 = lcnt[t], c1 = lcnt[t + 256];
    ssc[t] = c0; ssc[t + 256] = c1;
    __syncthreads();
    for (int o = 1; o < 512; o <<= 1) {
        int a0 = (t >= o) ? ssc[t - o] : 0;
        int a1 = ssc[t + 256 - o];
        __syncthreads();
        ssc[t] += a0; ssc[t + 256] += a1;
        __syncthreads();
    }
    int na = n0 + t, nb = n0 + t + 256;
    if (na < NNODES) { row_ptr[na] = p0 + ssc[t] - c0;       dinv[na] = rsqrtf((float)c0 + 1.0f); }
    if (nb < NNODES) { row_ptr[nb] = p0 + ssc[t + 256] - c1; dinv[nb] = rsqrtf((float)c1 + 1.0f); }
    if (b == 0 && t == 0) row_ptr[NNODES] = NEDGES;
}

// F: per-bucket ranking -> packed (bf16(dinv[src])<<16 | src) stream
__global__ __launch_bounds__(256) void phase2b(const u32* __restrict__ pairs,
                                               const int* __restrict__ bbase, const int* __restrict__ btot,
                                               const int* __restrict__ row_ptr, const float* __restrict__ dinv,
                                               u32* __restrict__ pw) {
    __shared__ int lcur[512];
    int b = blockIdx.x, t = threadIdx.x;
    int n0 = b << B2SHIFT;
    int na = n0 + t, nb = n0 + t + 256;
    lcur[t]       = (na < NNODES) ? row_ptr[na] : NEDGES;
    lcur[t + 256] = (nb < NNODES) ? row_ptr[nb] : NEDGES;
    __syncthreads();
    int p0 = bbase[b], p1 = p0 + btot[b];
    for (int p = p0 + t; p < p1; p += 256) {
        u32 pk = pairs[p];
        int dl = (int)(pk >> 16);
        int src = (int)(pk & 0xFFFFu);
        int pos = atomicAdd(&lcur[dl], 1);
        pw[pos] = ((u32)f2b(dinv[src]) << 16) | (u32)src;
    }
}

// ---------------- fused layer: agg (64 nodes -> LDS A-tile) + MFMA GEMM (64x256) ----------------
// out = [relu](A_agg @ W + b); A_agg[v] = dv*( dv*h[v] + sum_e w[e]*h[src[e]] )
// 512 threads = 8 waves; wave w aggregates rows w*8..w*8+7, then computes cols w*32..w*32+31.
// LDS chunk-XOR swizzle on 16B chunks: slot = c ^ (r&3)  (XOR with <=3 only touches low 2 bits).
template <int KT, bool RELU, bool OUT_BF16>
__global__ __launch_bounds__(512, 6) void fused_layer(const u16* __restrict__ h,
                                                      const int* __restrict__ row_ptr,
                                                      const u32* __restrict__ pw,
                                                      const float* __restrict__ dinv,
                                                      const u16* __restrict__ Wt,
                                                      const float* __restrict__ bias,
                                                      void* __restrict__ outp) {
    constexpr int VEC = KT / 64;   // 2 or 4 bf16 per lane per row
    constexpr int NK = KT / 32;    // k-steps
    __shared__ __align__(16) u16 As[64 * KT];
    __shared__ __align__(16) u16 Bs[256 * 32];
    const int tid = threadIdx.x;
    const int lane = tid & 63, w = tid >> 6;
    const int l15 = lane & 15, lhi = lane >> 4;
    const int m0 = blockIdx.x * 64;

    // ---- stage 1: aggregate 8 rows per wave into As ----
    for (int i = 0; i < 8; ++i) {
        const int r = w * 8 + i;
        const int v = m0 + r;
        float acc[VEC];
#pragma unroll
        for (int q = 0; q < VEC; ++q) acc[q] = 0.f;
        float dv = 0.f;
        if (v < NNODES) {
            const int e0 = row_ptr[v], e1 = row_ptr[v + 1];
            dv = dinv[v];
            const u16* sp = h + (size_t)v * KT + lane * VEC;
            if constexpr (VEC == 4) {
                ushort4 t = *(const ushort4*)sp;
                acc[0] = dv * b2f(t.x); acc[1] = dv * b2f(t.y); acc[2] = dv * b2f(t.z); acc[3] = dv * b2f(t.w);
            } else {
                ushort2 t = *(const ushort2*)sp;
                acc[0] = dv * b2f(t.x); acc[1] = dv * b2f(t.y);
            }
            for (int e = e0; e < e1; e += 8) {
                u32 pk[8];
#pragma unroll
                for (int u = 0; u < 8; ++u) {
                    int idx = e + u;
                    pk[u] = pw[idx < e1 ? idx : e1 - 1];
                }
                int   c[8];
                float wt[8];
#pragma unroll
                for (int u = 0; u < 8; ++u) {
                    c[u] = (int)(pk[u] & 0xFFFFu);
                    wt[u] = (e + u < e1) ? b2f((u16)(pk[u] >> 16)) : 0.0f;
                }
                if constexpr (VEC == 4) {
                    ushort4 rr[8];
#pragma unroll
                    for (int u = 0; u < 8; ++u)
                        rr[u] = *(const ushort4*)(h + (size_t)c[u] * KT + lane * 4);
#pragma unroll
                    for (int u = 0; u < 8; ++u) {
                        acc[0] += wt[u] * b2f(rr[u].x);
                        acc[1] += wt[u] * b2f(rr[u].y);
                        acc[2] += wt[u] * b2f(rr[u].z);
                        acc[3] += wt[u] * b2f(rr[u].w);
                    }
                } else {
                    ushort2 rr[8];
#pragma unroll
                    for (int u = 0; u < 8; ++u)
                        rr[u] = *(const ushort2*)(h + (size_t)c[u] * KT + lane * 2);
#pragma unroll
                    for (int u = 0; u < 8; ++u) {
                        acc[0] += wt[u] * b2f(rr[u].x);
                        acc[1] += wt[u] * b2f(rr[u].y);
                    }
                }
            }
        }
        // swizzled LDS write of this row's lane-slice
        if constexpr (VEC == 4) {
            ushort4 t;
            t.x = f2b(dv * acc[0]); t.y = f2b(dv * acc[1]); t.z = f2b(dv * acc[2]); t.w = f2b(dv * acc[3]);
            *(ushort4*)&As[r * KT + (((lane >> 1) ^ (r & 3)) * 8) + (lane & 1) * 4] = t;
        } else {
            ushort2 t;
            t.x = f2b(dv * acc[0]); t.y = f2b(dv * acc[1]);
            *(ushort2*)&As[r * KT + (((lane >> 2) ^ (r & 3)) * 8) + (lane & 3) * 2] = t;
        }
    }

    // ---- stage 2: GEMM 64xKT @ KTx256 ----
    f32x4 gacc[4][2] = {};
    const int r2 = tid >> 1, sc2 = (tid & 1) * 2;
    for (int ks = 0; ks < NK; ++ks) {
        const int k0 = ks * 32;
        const uint4* bp = (const uint4*)(Wt + (size_t)r2 * KT + k0 + sc2 * 8);
        uint4 bv0 = bp[0], bv1 = bp[1];
        __syncthreads();  // prior reads done (1st iter: As writes done)
        *(uint4*)&Bs[r2 * 32 + ((sc2 ^ (r2 & 3)) * 8)]       = bv0;
        *(uint4*)&Bs[r2 * 32 + (((sc2 + 1) ^ (r2 & 3)) * 8)] = bv1;
        __syncthreads();
        s16x8 af[4];
#pragma unroll
        for (int m = 0; m < 4; ++m) {
            int r = m * 16 + l15;
            af[m] = *(const s16x8*)&As[r * KT + ((((k0 >> 3) + lhi) ^ (r & 3)) * 8)];
        }
#pragma unroll
        for (int n = 0; n < 2; ++n) {
            int rb = w * 32 + n * 16 + l15;
            s16x8 bf_ = *(const s16x8*)&Bs[rb * 32 + ((lhi ^ (rb & 3)) * 8)];
#pragma unroll
            for (int m = 0; m < 4; ++m)
                gacc[m][n] = __builtin_amdgcn_mfma_f32_16x16x32_bf16(af[m], bf_, gacc[m][n], 0, 0, 0);
        }
    }

    // ---- epilogue: C/D layout col = lane&15, row = (lane>>4)*4 + reg ----
#pragma unroll
    for (int n = 0; n < 2; ++n) {
        int gcol = w * 32 + n * 16 + l15;
        float bb = bias[gcol];
#pragma unroll
        for (int m = 0; m < 4; ++m) {
            int gr0 = m0 + m * 16 + lhi * 4;
#pragma unroll
            for (int rr = 0; rr < 4; ++rr) {
                int gr = gr0 + rr;
                if (gr >= NNODES) continue;
                float vv = gacc[m][n][rr] + bb;
                if (RELU) vv = vv > 0.f ? vv : 0.f;
                if (OUT_BF16)
                    ((u16*)outp)[(size_t)gr * 256 + gcol] = f2b(vv);
                else
                    ((float*)outp)[(size_t)gr * 256 + gcol] = vv;
            }
        }
    }
}

// ---------------- launch ----------------
extern "C" void kernel_launch(void* const* d_in, const int* in_sizes, int n_in,
                              void* d_out, int out_size, void* d_ws, size_t ws_size,
                              hipStream_t stream) {
    const float* x  = (const float*)d_in[0];
    const void* edges = d_in[1];
    const float* W1 = (const float*)d_in[2];
    const float* b1 = (const float*)d_in[3];
    const float* W2 = (const float*)d_in[4];
    const float* b2 = (const float*)d_in[5];
    const float* W3 = (const float*)d_in[6];
    const float* b3 = (const float*)d_in[7];
    float* out = (float*)d_out;

    char* ws = (char*)d_ws;
    float* dinv   = (float*)(ws + OFF_DINV);
    int*   rowptr = (int*)(ws + OFF_ROWPTR);
    int*   cmat   = (int*)(ws + OFF_CMAT);
    int*   btot   = (int*)(ws + OFF_BTOT);
    int*   bbase  = (int*)(ws + OFF_BBASE);
    u32*   pairs  = (u32*)(ws + OFF_PAIRS);
    u32*   pw     = (u32*)(ws + OFF_PW);
    u16*   xb     = (u16*)(ws + OFF_XB);
    u16*   hb     = (u16*)(ws + OFF_HB);
    u16*   hb2    = (u16*)(ws + OFF_HB2);
    u16*   W1t    = (u16*)(ws + OFF_W1T);
    u16*   W2t    = (u16*)(ws + OFF_W2T);
    u16*   W3t    = (u16*)(ws + OFF_W3T);

    // CSR build + converts
    hist_conv<<<NBLK + 6250 + 640, 256, 0, stream>>>(edges, cmat, x, W1, W2, W3, xb, W1t, W2t, W3t);
    offset_kernel<<<NB2, 256, 0, stream>>>(cmat, btot);
    bscan_kernel<<<1, 128, 0, stream>>>(btot, bbase);
    scatter_kernel<<<NBLK, 256, 0, stream>>>(edges, cmat, bbase, pairs);
    phase2a<<<NB2, 256, 0, stream>>>(pairs, bbase, btot, rowptr, dinv);
    phase2b<<<NB2, 256, 0, stream>>>(pairs, bbase, btot, rowptr, dinv, pw);

    const int FB = (NNODES + 63) / 64;  // 782

    // fused layers
    fused_layer<F_IN, true, true><<<FB, 512, 0, stream>>>(xb, rowptr, pw, dinv, W1t, b1, hb);
    fused_layer<F_HID, true, true><<<FB, 512, 0, stream>>>(hb, rowptr, pw, dinv, W2t, b2, hb2);
    fused_layer<F_HID, false, false><<<FB, 512, 0, stream>>>(hb2, rowptr, pw, dinv, W3t, b3, out);
}

// Round 9
// 275.859 us; speedup vs baseline: 1.0870x; 1.0870x over previous
//
#include <hip/hip_runtime.h>
#include <hip/hip_bf16.h>

#define NNODES 50000
#define NEDGES 800000
#define F_IN 128
#define F_HID 256

using u16 = unsigned short;
using u32 = unsigned int;
using f32x4 = __attribute__((ext_vector_type(4))) float;
using s16x8 = __attribute__((ext_vector_type(8))) short;

constexpr int B2SHIFT = 9;                         // 512 nodes per coarse bucket
constexpr int NB2 = (NNODES + 511) >> 9;           // 98
constexpr int NBLK = 256;                          // scatter blocks
constexpr int EPB = NEDGES / NBLK;                 // 3125 edges per block (exact)

// ---------------- workspace layout (bytes) ----------------
constexpr size_t OFF_DINV   = 0;          // 200192
constexpr size_t OFF_ROWPTR = 200192;     // 200192
constexpr size_t OFF_CMAT   = 400384;     // 100352 (98*256*4)
constexpr size_t OFF_BTOT   = 500736;     // 1024
constexpr size_t OFF_BBASE  = 501760;     // 1024
constexpr size_t OFF_PAIRS  = 502784;     // 3200000 (800000 u32)
constexpr size_t OFF_PW     = 3702784;    // 3200000 (800000 u32 packed w|src)
constexpr size_t OFF_XB     = 6902784;    // 12800000 (50000x128 bf16)
constexpr size_t OFF_HB     = 19702784;   // 25600000 (50000x256 bf16)
constexpr size_t OFF_AGGB   = 45302784;   // 25600000
constexpr size_t OFF_W1T    = 70902784;   // 65536
constexpr size_t OFF_W2T    = 70968320;   // 131072
constexpr size_t OFF_W3T    = 71099392;   // 131072
// total ~71.2 MB

static __device__ __forceinline__ float b2f(u16 u) {
    union { unsigned int i; float f; } v;
    v.i = ((unsigned int)u) << 16;
    return v.f;
}
static __device__ __forceinline__ u16 f2b(float f) {
    __hip_bfloat16 h = __float2bfloat16(f);  // round-to-nearest
    return __builtin_bit_cast(u16, h);
}

// per-block edge-dtype detect: true => int64 layout.
static __device__ __forceinline__ bool detect_wide(const void* raw) {
    __shared__ int bad;
    if (threadIdx.x == 0) bad = 0;
    __syncthreads();
    unsigned long long v = ((const unsigned long long*)raw)[threadIdx.x & 255];
    if (v >= (unsigned long long)NNODES) atomicAdd(&bad, 1);
    __syncthreads();
    return bad == 0;
}

// ---------------- A: hist (blocks 0..255) + all fp32->bf16 converts (blocks 256..7145) ----------------
__global__ __launch_bounds__(256) void hist_conv(const void* __restrict__ raw, int* __restrict__ cmat,
                                                 const float* __restrict__ x,
                                                 const float* __restrict__ W1, const float* __restrict__ W2,
                                                 const float* __restrict__ W3, u16* __restrict__ xb,
                                                 u16* __restrict__ W1t, u16* __restrict__ W2t,
                                                 u16* __restrict__ W3t) {
    int bid = blockIdx.x;
    int t = threadIdx.x;
    if (bid < NBLK) {
        const bool wide = detect_wide(raw);
        __shared__ int h[NB2];
        if (t < NB2) h[t] = 0;
        __syncthreads();
        const int base = bid * EPB;
        for (int i = t; i < EPB; i += 256) {
            int e = base + i;
            int d = wide ? (int)((const long long*)raw)[NEDGES + e] : ((const int*)raw)[NEDGES + e];
            atomicAdd(&h[d >> B2SHIFT], 1);
        }
        __syncthreads();
        if (t < NB2) cmat[t * NBLK + bid] = h[t];
    } else if (bid < NBLK + 6250) {
        int i = (bid - NBLK) * 256 + t;  // 1,600,000 float4 units exactly
        float4 v = ((const float4*)x)[i];
        ushort4 o;
        o.x = f2b(v.x); o.y = f2b(v.y); o.z = f2b(v.z); o.w = f2b(v.w);
        ((ushort4*)xb)[i] = o;
    } else {
        int idx = (bid - NBLK - 6250) * 256 + t;  // 163840 = 32768 + 65536 + 65536
        if (idx < 32768) {
            int k = idx >> 8, n = idx & 255;
            W1t[n * 128 + k] = f2b(W1[idx]);
        } else if (idx < 98304) {
            int j = idx - 32768;
            int k = j >> 8, n = j & 255;
            W2t[n * 256 + k] = f2b(W2[j]);
        } else {
            int j = idx - 98304;
            int k = j >> 8, n = j & 255;
            W3t[n * 256 + k] = f2b(W3[j]);
        }
    }
}

// B: per-bucket exclusive scan over the 256 block-counts (bucket-local); bucket total out
__global__ __launch_bounds__(256) void offset_kernel(int* __restrict__ cmat, int* __restrict__ btot) {
    __shared__ int s[256];
    int b = blockIdx.x, t = threadIdx.x;
    int v = cmat[b * NBLK + t];
    s[t] = v;
    __syncthreads();
    for (int o = 1; o < 256; o <<= 1) {
        int tmp = (t >= o) ? s[t - o] : 0;
        __syncthreads();
        s[t] += tmp;
        __syncthreads();
    }
    cmat[b * NBLK + t] = s[t] - v;  // exclusive, bucket-local
    if (t == 255) btot[b] = s[255];
}

// C: exclusive scan of 98 bucket totals -> bucket bases
__global__ void bscan_kernel(const int* __restrict__ btot, int* __restrict__ bbase) {
    __shared__ int s[128];
    int t = threadIdx.x;
    int v = (t < NB2) ? btot[t] : 0;
    s[t] = v;
    __syncthreads();
    for (int o = 1; o < 128; o <<= 1) {
        int tmp = (t >= o) ? s[t - o] : 0;
        __syncthreads();
        s[t] += tmp;
        __syncthreads();
    }
    if (t < NB2) bbase[t] = s[t] - v;
}

// D: scatter edges into exact bucket regions; cursors in LDS (block-private)
__global__ __launch_bounds__(256) void scatter_kernel(const void* __restrict__ raw,
                                                      const int* __restrict__ cmat,
                                                      const int* __restrict__ bbase,
                                                      u32* __restrict__ pairs) {
    const bool wide = detect_wide(raw);
    __shared__ int cur[NB2];
    int t = threadIdx.x;
    if (t < NB2) cur[t] = cmat[t * NBLK + blockIdx.x] + bbase[t];
    __syncthreads();
    const int base = blockIdx.x * EPB;
    for (int i = t; i < EPB; i += 256) {
        int e = base + i;
        int s, d;
        if (wide) {
            const long long* p = (const long long*)raw;
            s = (int)p[e];
            d = (int)p[NEDGES + e];
        } else {
            const int* p = (const int*)raw;
            s = p[e];
            d = p[NEDGES + e];
        }
        int pos = atomicAdd(&cur[d >> B2SHIFT], 1);
        pairs[pos] = ((u32)(d & 511) << 16) | (u32)s;  // src < 50000 < 2^16
    }
}

// E: per-bucket degree count (LDS) + 512-wide LDS scan -> row_ptr + dinv
__global__ __launch_bounds__(256) void phase2a(const u32* __restrict__ pairs,
                                               const int* __restrict__ bbase, const int* __restrict__ btot,
                                               int* __restrict__ row_ptr, float* __restrict__ dinv) {
    __shared__ int lcnt[512];
    __shared__ int ssc[512];
    int b = blockIdx.x, t = threadIdx.x;
    int n0 = b << B2SHIFT;
    lcnt[t] = 0; lcnt[t + 256] = 0;
    __syncthreads();
    int p0 = bbase[b], p1 = p0 + btot[b];
    for (int p = p0 + t; p < p1; p += 256)
        atomicAdd(&lcnt[pairs[p] >> 16], 1);
    __syncthreads();
    int c0 = lcnt[t], c1 = lcnt[t + 256];
    ssc[t] = c0; ssc[t + 256] = c1;
    __syncthreads();
    for (int o = 1; o < 512; o <<= 1) {
        int a0 = (t >= o) ? ssc[t - o] : 0;
        int a1 = ssc[t + 256 - o];
        __syncthreads();
        ssc[t] += a0; ssc[t + 256] += a1;
        __syncthreads();
    }
    int na = n0 + t, nb = n0 + t + 256;
    if (na < NNODES) { row_ptr[na] = p0 + ssc[t] - c0;       dinv[na] = rsqrtf((float)c0 + 1.0f); }
    if (nb < NNODES) { row_ptr[nb] = p0 + ssc[t + 256] - c1; dinv[nb] = rsqrtf((float)c1 + 1.0f); }
    if (b == 0 && t == 0) row_ptr[NNODES] = NEDGES;
}

// F: per-bucket ranking -> packed (bf16(dinv[src])<<16 | src) stream
__global__ __launch_bounds__(256) void phase2b(const u32* __restrict__ pairs,
                                               const int* __restrict__ bbase, const int* __restrict__ btot,
                                               const int* __restrict__ row_ptr, const float* __restrict__ dinv,
                                               u32* __restrict__ pw) {
    __shared__ int lcur[512];
    int b = blockIdx.x, t = threadIdx.x;
    int n0 = b << B2SHIFT;
    int na = n0 + t, nb = n0 + t + 256;
    lcur[t]       = (na < NNODES) ? row_ptr[na] : NEDGES;
    lcur[t + 256] = (nb < NNODES) ? row_ptr[nb] : NEDGES;
    __syncthreads();
    int p0 = bbase[b], p1 = p0 + btot[b];
    for (int p = p0 + t; p < p1; p += 256) {
        u32 pk = pairs[p];
        int dl = (int)(pk >> 16);
        int src = (int)(pk & 0xFFFFu);
        int pos = atomicAdd(&lcur[dl], 1);
        pw[pos] = ((u32)f2b(dinv[src]) << 16) | (u32)src;
    }
}

// ---------------- aggregation (round-6 best: unroll-8, clamped unconditional loads) ----------------
// out[v] = dv * ( dv*h[v] + sum_e w[e]*h[src[e]] ),  pw[e] = bf16(dinv[src])<<16 | src
template <int F>
__global__ __launch_bounds__(256) void agg_kernel(const u16* __restrict__ h,
                                                  const int* __restrict__ row_ptr,
                                                  const u32* __restrict__ pw,
                                                  const float* __restrict__ dinv,
                                                  u16* __restrict__ outb) {
    constexpr int VEC = F / 64;  // 2 (F=128) or 4 (F=256) bf16 per lane
    int lane = threadIdx.x & 63;
    int v = __builtin_amdgcn_readfirstlane((int)(blockIdx.x * 4 + (threadIdx.x >> 6)));
    const size_t lo = (size_t)lane * VEC;

    const int e0 = row_ptr[v], e1 = row_ptr[v + 1];
    float dv = dinv[v];
    float acc[VEC];
    {
        const u16* p = h + (size_t)v * F + lo;
        if constexpr (VEC == 4) {
            ushort4 t = *(const ushort4*)p;
            acc[0] = dv * b2f(t.x); acc[1] = dv * b2f(t.y); acc[2] = dv * b2f(t.z); acc[3] = dv * b2f(t.w);
        } else {
            ushort2 t = *(const ushort2*)p;
            acc[0] = dv * b2f(t.x); acc[1] = dv * b2f(t.y);
        }
    }
    // unconditional clamped unroll-8: all loads always issue (max MLP), OOB slots get w=0
    for (int e = e0; e < e1; e += 8) {
        u32 pk[8];
#pragma unroll
        for (int u = 0; u < 8; ++u) {
            int idx = e + u;
            pk[u] = pw[idx < e1 ? idx : e1 - 1];  // safe: loop entered only if e1 > e0
        }
        int   c[8];
        float w[8];
#pragma unroll
        for (int u = 0; u < 8; ++u) {
            c[u] = (int)(pk[u] & 0xFFFFu);
            w[u] = (e + u < e1) ? b2f((u16)(pk[u] >> 16)) : 0.0f;
        }
        if constexpr (VEC == 4) {
            ushort4 r[8];
#pragma unroll
            for (int u = 0; u < 8; ++u)
                r[u] = *(const ushort4*)(h + (size_t)c[u] * F + lo);
#pragma unroll
            for (int u = 0; u < 8; ++u) {
                acc[0] += w[u] * b2f(r[u].x);
                acc[1] += w[u] * b2f(r[u].y);
                acc[2] += w[u] * b2f(r[u].z);
                acc[3] += w[u] * b2f(r[u].w);
            }
        } else {
            ushort2 r[8];
#pragma unroll
            for (int u = 0; u < 8; ++u)
                r[u] = *(const ushort2*)(h + (size_t)c[u] * F + lo);
#pragma unroll
            for (int u = 0; u < 8; ++u) {
                acc[0] += w[u] * b2f(r[u].x);
                acc[1] += w[u] * b2f(r[u].y);
            }
        }
    }
    u16* o = outb + (size_t)v * F + lo;
    if constexpr (VEC == 4) {
        ushort4 t;
        t.x = f2b(dv * acc[0]); t.y = f2b(dv * acc[1]); t.z = f2b(dv * acc[2]); t.w = f2b(dv * acc[3]);
        *(ushort4*)o = t;
    } else {
        ushort2 t;
        t.x = f2b(dv * acc[0]); t.y = f2b(dv * acc[1]);
        *(ushort2*)o = t;
    }
}

// ---------------- bf16 MFMA GEMM: out[M x 256] = A[M x KT] @ W[KT x 256] + b ----------------
template <int KT, bool RELU, bool OUT_BF16>
__global__ __launch_bounds__(256) void gemm_mfma(const u16* __restrict__ A, const u16* __restrict__ Wt,
                                                 const float* __restrict__ bias, void* __restrict__ outp,
                                                 int M) {
    constexpr int BM = 128, BN = 128, BK = 32;
    __shared__ __align__(16) u16 As[BM * BK];
    __shared__ __align__(16) u16 Bs[BN * BK];
    const int tid = threadIdx.x;
    const int lane = tid & 63, wid = tid >> 6;
    const int l15 = lane & 15, lhi = lane >> 4;
    const int m0 = blockIdx.x * BM, n0 = blockIdx.y * BN;
    const int wr = (wid >> 1) * 64, wc = (wid & 1) * 64;

    f32x4 acc[4][4] = {};

    const int sr = tid >> 1;        // staging row 0..127
    const int sc2 = (tid & 1) * 2;  // staging chunk base (0 or 2)

    for (int k0 = 0; k0 < KT; k0 += BK) {
        uint4 av0, av1, bv0, bv1;
        int ar = m0 + sr;
        if (ar < M) {
            const uint4* ap = (const uint4*)(A + (size_t)ar * KT + k0 + sc2 * 8);
            av0 = ap[0]; av1 = ap[1];
        } else {
            av0 = make_uint4(0, 0, 0, 0); av1 = av0;
        }
        const uint4* bp = (const uint4*)(Wt + (size_t)(n0 + sr) * KT + k0 + sc2 * 8);
        bv0 = bp[0]; bv1 = bp[1];

        __syncthreads();
        *(uint4*)&As[sr * BK + ((sc2 ^ (sr & 3)) * 8)]       = av0;
        *(uint4*)&As[sr * BK + (((sc2 + 1) ^ (sr & 3)) * 8)] = av1;
        *(uint4*)&Bs[sr * BK + ((sc2 ^ (sr & 3)) * 8)]       = bv0;
        *(uint4*)&Bs[sr * BK + (((sc2 + 1) ^ (sr & 3)) * 8)] = bv1;
        __syncthreads();

        s16x8 af[4], bfr[4];
#pragma unroll
        for (int m = 0; m < 4; ++m) {
            int r = wr + m * 16 + l15;
            af[m] = *(const s16x8*)&As[r * BK + ((lhi ^ (r & 3)) * 8)];
        }
#pragma unroll
        for (int n = 0; n < 4; ++n) {
            int r = wc + n * 16 + l15;
            bfr[n] = *(const s16x8*)&Bs[r * BK + ((lhi ^ (r & 3)) * 8)];
        }
#pragma unroll
        for (int m = 0; m < 4; ++m)
#pragma unroll
            for (int n = 0; n < 4; ++n)
                acc[m][n] = __builtin_amdgcn_mfma_f32_16x16x32_bf16(af[m], bfr[n], acc[m][n], 0, 0, 0);
    }

    // epilogue: C/D layout col = lane&15, row = (lane>>4)*4 + reg
#pragma unroll
    for (int n = 0; n < 4; ++n) {
        int gcol = n0 + wc + n * 16 + l15;
        float bb = bias[gcol];
#pragma unroll
        for (int m = 0; m < 4; ++m) {
            int gr0 = m0 + wr + m * 16 + lhi * 4;
#pragma unroll
            for (int r = 0; r < 4; ++r) {
                int gr = gr0 + r;
                if (gr >= M) continue;
                float vv = acc[m][n][r] + bb;
                if (RELU) vv = vv > 0.f ? vv : 0.f;
                if (OUT_BF16)
                    ((u16*)outp)[(size_t)gr * 256 + gcol] = f2b(vv);
                else
                    ((float*)outp)[(size_t)gr * 256 + gcol] = vv;
            }
        }
    }
}

// ---------------- launch ----------------
extern "C" void kernel_launch(void* const* d_in, const int* in_sizes, int n_in,
                              void* d_out, int out_size, void* d_ws, size_t ws_size,
                              hipStream_t stream) {
    const float* x  = (const float*)d_in[0];
    const void* edges = d_in[1];
    const float* W1 = (const float*)d_in[2];
    const float* b1 = (const float*)d_in[3];
    const float* W2 = (const float*)d_in[4];
    const float* b2 = (const float*)d_in[5];
    const float* W3 = (const float*)d_in[6];
    const float* b3 = (const float*)d_in[7];
    float* out = (float*)d_out;

    char* ws = (char*)d_ws;
    float* dinv   = (float*)(ws + OFF_DINV);
    int*   rowptr = (int*)(ws + OFF_ROWPTR);
    int*   cmat   = (int*)(ws + OFF_CMAT);
    int*   btot   = (int*)(ws + OFF_BTOT);
    int*   bbase  = (int*)(ws + OFF_BBASE);
    u32*   pairs  = (u32*)(ws + OFF_PAIRS);
    u32*   pw     = (u32*)(ws + OFF_PW);
    u16*   xb     = (u16*)(ws + OFF_XB);
    u16*   hb     = (u16*)(ws + OFF_HB);
    u16*   aggb   = (u16*)(ws + OFF_AGGB);
    u16*   W1t    = (u16*)(ws + OFF_W1T);
    u16*   W2t    = (u16*)(ws + OFF_W2T);
    u16*   W3t    = (u16*)(ws + OFF_W3T);

    // CSR build + converts (hist+convert merged)
    hist_conv<<<NBLK + 6250 + 640, 256, 0, stream>>>(edges, cmat, x, W1, W2, W3, xb, W1t, W2t, W3t);
    offset_kernel<<<NB2, 256, 0, stream>>>(cmat, btot);
    bscan_kernel<<<1, 128, 0, stream>>>(btot, bbase);
    scatter_kernel<<<NBLK, 256, 0, stream>>>(edges, cmat, bbase, pairs);
    phase2a<<<NB2, 256, 0, stream>>>(pairs, bbase, btot, rowptr, dinv);
    phase2b<<<NB2, 256, 0, stream>>>(pairs, bbase, btot, rowptr, dinv, pw);

    const int AGG_GRID = NNODES / 4;  // 12500
    dim3 ggrid((NNODES + 127) / 128, 2);

    // layer 1
    agg_kernel<F_IN><<<AGG_GRID, 256, 0, stream>>>(xb, rowptr, pw, dinv, aggb);
    gemm_mfma<F_IN, true, true><<<ggrid, 256, 0, stream>>>(aggb, W1t, b1, hb, NNODES);

    // layer 2
    agg_kernel<F_HID><<<AGG_GRID, 256, 0, stream>>>(hb, rowptr, pw, dinv, aggb);
    gemm_mfma<F_HID, true, true><<<ggrid, 256, 0, stream>>>(aggb, W2t, b2, hb, NNODES);

    // layer 3
    agg_kernel<F_HID><<<AGG_GRID, 256, 0, stream>>>(hb, rowptr, pw, dinv, aggb);
    gemm_mfma<F_HID, false, false><<<ggrid, 256, 0, stream>>>(aggb, W3t, b3, out, NNODES);
}